// Round 8
// baseline (157.076 us; speedup 1.0000x reference)
//
#include <hip/hip_runtime.h>
#include <hip/hip_bf16.h>

// C = triu( triu(A) @ triu(B) ), N=4096, fp32 in/out.
// Split-K bf16 MFMA, KSTEP=32, LDS double-buffer (40960 B -> 4 blocks/CU),
// one barrier per K-step. Sub-blocks enumerated grouped by shared A-panel
// (bi, chunk) with bj innermost; chunked XCD swizzle keeps each sharing
// group on one XCD's L2. Kernel 1 zeroes C; kernel 2 accumulates partials
// with device fp32 atomics.

#define NDIM 4096
#define BM 128
#define BN 128
#define KSTEP 32
#define NBLK (NDIM / BM)                  // 32
#define NSUB 1000                         // sum over tiles of ceil(L/8)
#define LSTR 80                           // LDS row stride (64B data + 16B pad)
#define TILEB (BM * LSTR)                 // 10240 B per tile

typedef __attribute__((ext_vector_type(8))) short short8;
typedef __attribute__((ext_vector_type(4))) float f32x4;
typedef __attribute__((ext_vector_type(4))) float floatx4;

__device__ __forceinline__ int loff(int row, int kb) {
    return row * LSTR + kb;   // kb = byte offset within the 64B row data
}

// packed fp32x2 -> bf16x2 (RNE) -- compiler emits v_cvt_pk_bf16_f32
__device__ __forceinline__ unsigned pkbf(float a, float b) {
    __hip_bfloat162 h = __float22bfloat162_rn(make_float2(a, b));
    unsigned r;
    __builtin_memcpy(&r, &h, sizeof(r));
    return r;
}

__global__ __launch_bounds__(256) void zero_c_kernel(float* __restrict__ C) {
    const float4 z = make_float4(0.f, 0.f, 0.f, 0.f);
    const size_t total = (size_t)NDIM * NDIM / 4;
    for (size_t i = blockIdx.x * 256 + threadIdx.x; i < total;
         i += (size_t)gridDim.x * 256)
        reinterpret_cast<float4*>(C)[i] = z;
}

__global__ __launch_bounds__(256, 4) void trimm_split_kernel(
    const float* __restrict__ A, const float* __restrict__ B,
    float* __restrict__ C) {
    const int tid = threadIdx.x;

    // ---- chunked XCD swizzle: contiguous logical ids -> same XCD ----
    const int logical = (blockIdx.x & 7) * (NSUB / 8) + (blockIdx.x >> 3);

    // ---- decode logical id -> (bi, ch, bj); groups share A panel ----
    int bi, ch = 0, bj = 0;
    {
        int r = logical;
        for (bi = 0; bi < NBLK; ++bi) {
            bool found = false;
            for (ch = 0;; ++ch) {
                const int c = NBLK - bi - 8 * ch;   // # bj sharing (bi,ch)
                if (c <= 0) break;
                if (r < c) { bj = bi + 8 * ch + r; found = true; break; }
                r -= c;
            }
            if (found) break;
        }
    }

    const int row0 = bi * BM;
    const int col0 = bj * BN;
    const int kstart = row0 + ch * 1024;
    const int kend = min(col0 + BN, kstart + 1024);

    __shared__ __align__(16) char lds[2][2 * TILEB];  // 40960 B total

    floatx4 acc[4][4];
    const floatx4 fz = {0.f, 0.f, 0.f, 0.f};
#pragma unroll
    for (int m = 0; m < 4; ++m)
#pragma unroll
        for (int n = 0; n < 4; ++n) acc[m][n] = fz;

    const int wv = tid >> 6;
    const int wr = (wv >> 1) * 64;
    const int wc = (wv & 1) * 64;
    const int lane = tid & 63;
    const int fr = lane & 15;
    const int kb = (lane >> 4) * 16;

    // A staging: thread owns 4 float4 chunks; f = tid+256j ->
    //   row = f>>3 (8 float4 per 32-float row), LDS byte = (f&7)*8
    int arow[4], abyt[4];
#pragma unroll
    for (int j = 0; j < 4; ++j) {
        const int f = tid + 256 * j;
        arow[j] = f >> 3;
        abyt[j] = (f & 7) * 8;
    }
    // B staging: one col per thread (stride-1 cols => 8-way write max),
    // k-half of 16
    const int bn = tid & 127;
    const int bkh = (tid >> 7) * 16;

    f32x4 pa[4];
    float pb[16];

    auto load_tiles = [&](int kt) {
#pragma unroll
        for (int j = 0; j < 4; ++j)
            pa[j] = *reinterpret_cast<const f32x4*>(
                &A[(size_t)(row0 + arow[j]) * NDIM + kt + abyt[j] / 2]);
#pragma unroll
        for (int kk = 0; kk < 16; ++kk)
            pb[kk] = B[(size_t)(kt + bkh + kk) * NDIM + col0 + bn];
    };
    auto write_tiles = [&](char* base) {
        char* lA = base;
        char* lB = base + TILEB;
#pragma unroll
        for (int j = 0; j < 4; ++j) {
            uint2 w;
            w.x = pkbf(pa[j][0], pa[j][1]);
            w.y = pkbf(pa[j][2], pa[j][3]);
            *reinterpret_cast<uint2*>(lA + loff(arow[j], abyt[j])) = w;
        }
        {
            uint4 w0, w1;
            w0.x = pkbf(pb[0], pb[1]);
            w0.y = pkbf(pb[2], pb[3]);
            w0.z = pkbf(pb[4], pb[5]);
            w0.w = pkbf(pb[6], pb[7]);
            w1.x = pkbf(pb[8], pb[9]);
            w1.y = pkbf(pb[10], pb[11]);
            w1.z = pkbf(pb[12], pb[13]);
            w1.w = pkbf(pb[14], pb[15]);
            *reinterpret_cast<uint4*>(lB + loff(bn, bkh * 2)) = w0;
            *reinterpret_cast<uint4*>(lB + loff(bn, bkh * 2 + 16)) = w1;
        }
    };

    // ---- prologue: stage tile 0 into buffer 0 ----
    load_tiles(kstart);
    write_tiles(lds[0]);

    int cur = 0;
    for (int kt = kstart; kt < kend; kt += KSTEP) {
        __syncthreads();   // buf[cur] writes visible to all waves

        const int kn = kt + KSTEP;
        if (kn < kend) load_tiles(kn);   // in flight under the MFMAs below

        char* lA = lds[cur];
        char* lB = lds[cur] + TILEB;
        short8 af[4], bf[4];
#pragma unroll
        for (int m = 0; m < 4; ++m)
            af[m] = *reinterpret_cast<const short8*>(
                lA + loff(wr + m * 16 + fr, kb));
#pragma unroll
        for (int n = 0; n < 4; ++n)
            bf[n] = *reinterpret_cast<const short8*>(
                lB + loff(wc + n * 16 + fr, kb));
#pragma unroll
        for (int m = 0; m < 4; ++m)
#pragma unroll
            for (int n = 0; n < 4; ++n)
                acc[m][n] = __builtin_amdgcn_mfma_f32_16x16x32_bf16(
                    af[m], bf[n], acc[m][n], 0, 0, 0);

        if (kn < kend) write_tiles(lds[cur ^ 1]);  // other buffer: no race
        cur ^= 1;
    }

    // ---- epilogue: atomic accumulate (C pre-zeroed); mask row<=col ----
    // C/D layout: col=lane&15, row=(lane>>4)*4+reg
#pragma unroll
    for (int m = 0; m < 4; ++m) {
        const int rbase = row0 + wr + m * 16 + (lane >> 4) * 4;
#pragma unroll
        for (int n = 0; n < 4; ++n) {
            const int col = col0 + wc + n * 16 + fr;
#pragma unroll
            for (int r = 0; r < 4; ++r) {
                const int row = rbase + r;
                if (row <= col)
                    unsafeAtomicAdd(&C[(size_t)row * NDIM + col],
                                    acc[m][n][r]);
            }
        }
    }
}

extern "C" void kernel_launch(void* const* d_in, const int* in_sizes, int n_in,
                              void* d_out, int out_size, void* d_ws,
                              size_t ws_size, hipStream_t stream) {
    const float* A = (const float*)d_in[0];
    const float* B = (const float*)d_in[1];
    float* C = (float*)d_out;
    zero_c_kernel<<<dim3(2048), dim3(256), 0, stream>>>(C);
    trimm_split_kernel<<<dim3(NSUB), dim3(256), 0, stream>>>(A, B, C);
}